// Round 11
// baseline (199.927 us; speedup 1.0000x reference)
//
#include <hip/hip_runtime.h>

#define HID 64
#define IN_C 16

typedef __attribute__((ext_vector_type(8))) short short8;
typedef __attribute__((ext_vector_type(4))) float f32x4;

__device__ __forceinline__ float bitsf(unsigned u) { return __uint_as_float(u); }
__device__ __forceinline__ float lanebcf(float v, int l) {
    return __int_as_float(__builtin_amdgcn_readlane(__float_as_int(v), l));
}
__device__ __forceinline__ float f4c(const float4& a, int c) {
    switch (c & 3) { case 0: return a.x; case 1: return a.y; case 2: return a.z; default: return a.w; }
}

// ---- k_init: zero cnt8 + pack stacked weights [WZ | W1+WQ | W1] into MFMA B-frags ----
// WZ = Mt@W1 (bias 0), WPQ = W1 + Mb@W1 (bias b1 + bM0@W1), P-tile = W1 (bias b1).
__global__ void k_init(const float* __restrict__ M0, const float* __restrict__ W1,
                       const float* __restrict__ bM0, const float* __restrict__ b1,
                       int* __restrict__ cnt8, int M4,
                       ushort* __restrict__ WPhi, ushort* __restrict__ WPlo,
                       float* __restrict__ bias192) {
    int tid = blockIdx.x * 256 + threadIdx.x;
    int stride = gridDim.x * 256;
    int4 z4 = {0, 0, 0, 0};
    for (int i = tid; i < M4; i += stride) reinterpret_cast<int4*>(cnt8)[i] = z4;

    if (tid < 64 * 192) {
        int cc = tid % 192;
        int k  = tid / 192;
        float w;
        if (cc < 64) {
            float a = 0.f;
#pragma unroll
            for (int m = 0; m < HID; ++m) a = fmaf(M0[k * HID + m], W1[m * HID + cc], a);
            w = a;
        } else if (cc < 128) {
            int c = cc - 64;
            float a = W1[k * HID + c];
#pragma unroll
            for (int m = 0; m < HID; ++m) a = fmaf(M0[(HID + k) * HID + m], W1[m * HID + c], a);
            w = a;
        } else {
            w = W1[k * HID + (cc - 128)];
        }
        unsigned wb = __float_as_uint(w);
        ushort hi = (ushort)(wb >> 16);
        float hif = __uint_as_float(wb & 0xffff0000u);
        ushort lo = (ushort)(__float_as_uint(w - hif) >> 16);
        int ct = cc >> 4, s = k >> 5, l = ((k >> 3) & 3) * 16 + (cc & 15), j = k & 7;
        int fi = ((ct * 2 + s) * 64 + l) * 8 + j;
        WPhi[fi] = hi;
        WPlo[fi] = lo;
        if (k == 0) {
            float bv;
            if (cc < 64) bv = 0.f;
            else if (cc < 128) {
                int c = cc - 64;
                float a = b1[c];
#pragma unroll
                for (int m = 0; m < HID; ++m) a = fmaf(bM0[m], W1[m * HID + c], a);
                bv = a;
            } else bv = b1[cc - 128];
            bias192[cc] = bv;
        }
    }
}

// ---- fused: batched fire-and-forget hist + MFMA precompute ----
__global__ __launch_bounds__(256) void k_pre(
    const float* __restrict__ x, const float* __restrict__ W0, const float* __restrict__ b0,
    const ushort* __restrict__ WPhi, const ushort* __restrict__ WPlo,
    const float* __restrict__ bias192,
    ushort* __restrict__ zb, float* __restrict__ PQ, float* __restrict__ Pp, int N,
    const int* __restrict__ ei, int* __restrict__ cnt8, int E)
{
    __shared__ ushort hhi[64 * 64];
    __shared__ ushort hlo[64 * 64];

    int tid  = threadIdx.x;
    int lane = tid & 63;
    int w    = tid >> 6;
    int n0   = blockIdx.x * 64;

    // --- issue compute loads FIRST (oldest in vmcnt FIFO: their uses won't drain atomics) ---
    float w0c[IN_C];
#pragma unroll
    for (int k = 0; k < IN_C; ++k) w0c[k] = W0[k * HID + lane];
    float b0l = b0[lane];

    short8 Bhi[3][2], Blo[3][2];
    float bias[3];
#pragma unroll
    for (int i = 0; i < 3; ++i) {
        int ct = w * 3 + i;
#pragma unroll
        for (int s = 0; s < 2; ++s) {
            int fi = ((ct * 2 + s) * 64 + lane) * 8;
            Bhi[i][s] = *reinterpret_cast<const short8*>(WPhi + fi);
            Blo[i][s] = *reinterpret_cast<const short8*>(WPlo + fi);
        }
        bias[i] = bias192[ct * 16 + (lane & 15)];
    }

    int nx = n0 + w * 16 + (lane >> 2);
    float4 xq = make_float4(0.f, 0.f, 0.f, 0.f);
    if (nx < N) xq = *reinterpret_cast<const float4*>(x + (size_t)nx * IN_C + (lane & 3) * 4);

    // --- hist slice: 8 batched dst loads, then 8 return-free atomics (fire-and-forget) ---
    {
        int xcd = blockIdx.x & 7;
        int idx = blockIdx.x >> 3;
        int minBX = gridDim.x >> 3;
        int CH = (E + 7) / 8;
        int e0 = xcd * CH;
        int e1 = min(e0 + CH, E);
        int SC = (CH + minBX - 1) / minBX;
        int s0 = e0 + idx * SC;
        int s1 = min(s0 + SC, e1);
        int base = s0 + tid;
        int dsts[8];
        int cnt = 0;
#pragma unroll
        for (int u = 0; u < 8; ++u) {
            int e = base + u * 256;
            if (e < s1) { dsts[u] = ei[E + e]; cnt = u + 1; }
        }
        int* cx = cnt8 + (size_t)xcd * N;
#pragma unroll
        for (int u = 0; u < 8; ++u)
            if (u < cnt) atomicAdd(&cx[dsts[u]], 1);
    }

    // --- phase 1: wave-parallel x -> h (16 nodes/wave), split bf16, swizzled LDS ---
#pragma unroll
    for (int nn = 0; nn < 16; ++nn) {
        float acc = b0l;
#pragma unroll
        for (int k = 0; k < IN_C; ++k)
            acc = fmaf(lanebcf(f4c(xq, k & 3), 4 * nn + (k >> 2)), w0c[k], acc);
        float h = fmaxf(acc, 0.f);
        unsigned hb = __float_as_uint(h);
        ushort hi = (ushort)(hb >> 16);
        float hif = __uint_as_float(hb & 0xffff0000u);
        ushort lo = (ushort)(__float_as_uint(h - hif) >> 16);
        int nl = w * 16 + nn;
        int u  = ((lane >> 3) ^ (nl & 7));
        int off = nl * 64 + u * 8 + (lane & 7);
        hhi[off] = hi;
        hlo[off] = lo;
    }
    __syncthreads();

    // --- phase 2: MFMA ---
#pragma unroll
    for (int st = 0; st < 4; ++st) {
        int nloc = st * 16 + (lane & 15);
        short8 Ahi[2], Alo[2];
#pragma unroll
        for (int s = 0; s < 2; ++s) {
            int u = (s * 4 + (lane >> 4)) ^ (nloc & 7);
            int off = nloc * 64 + u * 8;
            Ahi[s] = *reinterpret_cast<const short8*>(hhi + off);
            Alo[s] = *reinterpret_cast<const short8*>(hlo + off);
        }
#pragma unroll
        for (int i = 0; i < 3; ++i) {
            int ct = w * 3 + i;
            f32x4 acc = {bias[i], bias[i], bias[i], bias[i]};
#pragma unroll
            for (int s = 0; s < 2; ++s) {
                acc = __builtin_amdgcn_mfma_f32_16x16x32_bf16(Ahi[s], Bhi[i][s], acc, 0, 0, 0);
                acc = __builtin_amdgcn_mfma_f32_16x16x32_bf16(Ahi[s], Blo[i][s], acc, 0, 0, 0);
                acc = __builtin_amdgcn_mfma_f32_16x16x32_bf16(Alo[s], Bhi[i][s], acc, 0, 0, 0);
                acc = __builtin_amdgcn_mfma_f32_16x16x32_bf16(Alo[s], Blo[i][s], acc, 0, 0, 0);
            }
            int ch = ct * 16 + (lane & 15);
#pragma unroll
            for (int r = 0; r < 4; ++r) {
                int n = n0 + st * 16 + (lane >> 4) * 4 + r;
                if (n >= N) continue;
                float v = acc[r];
                if (ch < 64) {
                    unsigned u = __float_as_uint(v);
                    unsigned rr = (u + 0x7fffu + ((u >> 16) & 1u)) >> 16;
                    zb[(size_t)n * HID + ch] = (ushort)rr;
                } else if (ch < 128) {
                    PQ[(size_t)n * HID + (ch - 64)] = v;
                } else {
                    Pp[(size_t)n * HID + (ch - 128)] = v;
                }
            }
        }
    }
}

// ---- exclusive scan over M=8N elements, 16 per thread (4096/block) ----
__global__ void k_scan1(const int* __restrict__ cnt, int* __restrict__ rs,
                        int* __restrict__ bsum, int M) {
    __shared__ int lds[256];
    int t = threadIdx.x;
    int base = blockIdx.x * 4096 + t * 16;
    int v[16];
    if (base + 16 <= M) {
#pragma unroll
        for (int u = 0; u < 4; ++u) {
            int4 w = *reinterpret_cast<const int4*>(cnt + base + u * 4);
            v[u * 4 + 0] = w.x; v[u * 4 + 1] = w.y; v[u * 4 + 2] = w.z; v[u * 4 + 3] = w.w;
        }
    } else {
#pragma unroll
        for (int u = 0; u < 16; ++u) v[u] = (base + u < M) ? cnt[base + u] : 0;
    }
    int run = 0;
#pragma unroll
    for (int u = 0; u < 16; ++u) { int tv = v[u]; v[u] = run; run += tv; }
    lds[t] = run;
    __syncthreads();
#pragma unroll
    for (int off = 1; off < 256; off <<= 1) {
        int xw = (t >= off) ? lds[t - off] : 0;
        __syncthreads();
        lds[t] += xw;
        __syncthreads();
    }
    int excl = lds[t] - run;
    if (t == 255) bsum[blockIdx.x] = lds[255];
#pragma unroll
    for (int u = 0; u < 16; ++u)
        if (base + u < M) rs[base + u] = excl + v[u];
}

// rs[i] += exscan(bsum)[i>>12]; cur[i]=rs[i]; rs[M]=E
__global__ void k_scan_add(int* __restrict__ rs, int* __restrict__ cur,
                           const int* __restrict__ bsum, int NB, int M, int E) {
    __shared__ int lds[256];
    __shared__ int excl[256];
    int t = threadIdx.x;
    int v = (t < NB) ? bsum[t] : 0;
    lds[t] = v;
    __syncthreads();
#pragma unroll
    for (int off = 1; off < 256; off <<= 1) {
        int xw = (t >= off) ? lds[t - off] : 0;
        __syncthreads();
        lds[t] += xw;
        __syncthreads();
    }
    excl[t] = lds[t] - v;
    __syncthreads();
    int i = blockIdx.x * 256 + t;
    if (i < M) {
        int val = rs[i] + excl[i >> 12];
        rs[i] = val;
        cur[i] = val;
    }
    if (i == 0) rs[M] = E;
}

// ---- per-XCD scatter, 8-deep batched cursor atomics ----
__global__ void k_scatter8(const int* __restrict__ ei, int* __restrict__ cur8,
                           int* __restrict__ csr8, int E, int N) {
    int xcd = blockIdx.x & 7;
    int o   = blockIdx.x >> 3;
    int Sx  = gridDim.x >> 3;
    int CH  = (E + 7) / 8;
    int e0  = xcd * CH;
    int e1  = min(e0 + CH, E);
    int SC  = (CH + Sx - 1) / Sx;
    int s0  = e0 + o * SC;
    int s1  = min(s0 + SC, e1);
    int base = s0 + (int)threadIdx.x;
    int* cx = cur8 + (size_t)xcd * N;

    int srcs[8], dsts[8];
    int cnt = 0;
#pragma unroll
    for (int u = 0; u < 8; ++u) {
        int e = base + u * 256;
        if (e < s1) { srcs[u] = ei[e]; dsts[u] = ei[E + e]; cnt = u + 1; }
    }
    int pos[8];
#pragma unroll
    for (int u = 0; u < 8; ++u)
        if (u < cnt) pos[u] = atomicAdd(&cx[dsts[u]], 1);
#pragma unroll
    for (int u = 0; u < 8; ++u)
        if (u < cnt) csr8[pos[u]] = srcs[u];
}

// ---- bf16 gather (2 edges/round per 16-lane group) + elementwise epilogue ----
__global__ __launch_bounds__(256) void k_final(
    const ushort* __restrict__ zb, const float* __restrict__ PQ, const float* __restrict__ Pp,
    const int* __restrict__ rs8f, const int* __restrict__ csr8,
    const float* __restrict__ W2, const float* __restrict__ b2,
    float* __restrict__ out, int N)
{
    int lane = threadIdx.x & 63;
    int g    = lane >> 4;
    int ql   = lane & 15;
    int oct  = ql & 7;
    int half = ql >> 3;
    int wid  = (blockIdx.x * 256 + threadIdx.x) >> 6;
    int nw   = (gridDim.x * 256) >> 6;

    int c0 = oct * 8 + half * 4;
    float4 w2v = *reinterpret_cast<const float4*>(W2 + c0);
    float b2s = b2[0];

    for (int n0 = wid * 4; n0 < N; n0 += nw * 4) {
        int ng   = n0 + g;
        bool okg = ng < N;

        int rv = okg ? rs8f[(size_t)oct * N + ng + half] : 0;
        int bx[8], cum[8];
        int dsum = 0;
#pragma unroll
        for (int xx = 0; xx < 8; ++xx) {
            int bb = __shfl(rv, g * 16 + xx);
            int ee = __shfl(rv, g * 16 + 8 + xx);
            bx[xx] = bb;
            cum[xx] = dsum;
            dsum += (ee - bb);
        }
        int deg = dsum;
        int md = deg;
        md = max(md, __shfl_xor(md, 16));
        md = max(md, __shfl_xor(md, 32));

        float acc[8];
#pragma unroll
        for (int i = 0; i < 8; ++i) acc[i] = 0.f;

        for (int c = 0; c < md; c += 32) {
            int j0 = c + ql, j1 = c + 16 + ql;
            int a0 = bx[0] + j0, a1 = bx[0] + j1;
#pragma unroll
            for (int xx = 1; xx < 8; ++xx) {
                a0 = (j0 >= cum[xx]) ? (bx[xx] + (j0 - cum[xx])) : a0;
                a1 = (j1 >= cum[xx]) ? (bx[xx] + (j1 - cum[xx])) : a1;
            }
            int ia = (j0 < deg) ? csr8[a0] : -1;
            int ib = (j1 < deg) ? csr8[a1] : -1;
#pragma unroll
            for (int tb = 0; tb < 4; ++tb) {
                if (tb > 0 && md <= c + 8 * tb) break;
                int srcs[4];
#pragma unroll
                for (int t4 = 0; t4 < 4; ++t4) {
                    int t = tb * 4 + t4;
                    int e = 2 * t + half;
                    srcs[t4] = __shfl(tb < 2 ? ia : ib, g * 16 + (e & 15));
                }
                uint4 rw[4];
#pragma unroll
                for (int t4 = 0; t4 < 4; ++t4) {
                    int s = srcs[t4] < 0 ? 0 : srcs[t4];
                    rw[t4] = *reinterpret_cast<const uint4*>(zb + (size_t)s * HID + oct * 8);
                }
#pragma unroll
                for (int t4 = 0; t4 < 4; ++t4) {
                    if (srcs[t4] >= 0) {
                        uint4 wv = rw[t4];
                        acc[0] += bitsf(wv.x << 16); acc[1] += bitsf(wv.x & 0xffff0000u);
                        acc[2] += bitsf(wv.y << 16); acc[3] += bitsf(wv.y & 0xffff0000u);
                        acc[4] += bitsf(wv.z << 16); acc[5] += bitsf(wv.z & 0xffff0000u);
                        acc[6] += bitsf(wv.w << 16); acc[7] += bitsf(wv.w & 0xffff0000u);
                    }
                }
            }
        }
#pragma unroll
        for (int i = 0; i < 8; ++i) acc[i] += __shfl_xor(acc[i], 8);

        float s0 = half ? acc[4] : acc[0];
        float s1 = half ? acc[5] : acc[1];
        float s2 = half ? acc[6] : acc[2];
        float s3 = half ? acc[7] : acc[3];

        float4 base = make_float4(0.f, 0.f, 0.f, 0.f);
        if (okg) {
            base = *reinterpret_cast<const float4*>(PQ + (size_t)ng * HID + c0);
            if (deg == 0)
                base = *reinterpret_cast<const float4*>(Pp + (size_t)ng * HID + c0);
        }
        float rcpd = (deg > 0) ? (1.f / (float)deg) : 0.f;
        float y0 = base.x + s0 * rcpd;
        float y1 = base.y + s1 * rcpd;
        float y2 = base.z + s2 * rcpd;
        float y3 = base.w + s3 * rcpd;

        float part = fmaxf(y0, 0.f) * w2v.x + fmaxf(y1, 0.f) * w2v.y +
                     fmaxf(y2, 0.f) * w2v.z + fmaxf(y3, 0.f) * w2v.w;
#pragma unroll
        for (int off = 1; off < 16; off <<= 1) part += __shfl_xor(part, off);
        if (ql == 0 && okg) out[ng] = part + b2s;
    }
}

extern "C" void kernel_launch(void* const* d_in, const int* in_sizes, int n_in,
                              void* d_out, int out_size, void* d_ws, size_t ws_size,
                              hipStream_t stream) {
    const float* x   = (const float*)d_in[0];
    const int*   ei  = (const int*)d_in[1];
    const float* W0  = (const float*)d_in[2];
    const float* b0  = (const float*)d_in[3];
    const float* W1  = (const float*)d_in[4];
    const float* b1  = (const float*)d_in[5];
    const float* W2  = (const float*)d_in[6];
    const float* b2  = (const float*)d_in[7];
    const float* M0  = (const float*)d_in[8];
    const float* bM0 = (const float*)d_in[9];

    int N = in_sizes[0] / IN_C;
    int E = in_sizes[1] / 2;
    int M = 8 * N;
    int NB = (M + 4095) / 4096;   // <= 256 for N <= 131072

    ushort* zb     = (ushort*)d_ws;                   // N*64 bf16
    float*  PQ     = (float*)(zb + (size_t)N * HID);  // N*64
    float*  Pp     = PQ + (size_t)N * HID;            // N*64
    ushort* WPhi   = (ushort*)(Pp + (size_t)N * HID); // 12288
    ushort* WPlo   = WPhi + 12288;                    // 12288
    float*  bias192= (float*)(WPlo + 12288);          // 192
    int*    cnt8   = (int*)(bias192 + 192);           // 8N
    int*    rs8f   = cnt8 + (size_t)M;                // 8N+1
    int*    cur8   = rs8f + (size_t)M + 1;            // 8N
    int*    bsum   = cur8 + (size_t)M;                // 256
    int*    csr8   = bsum + 256;                      // E
    float*  out    = (float*)d_out;

    int npre = (N + 63) / 64;

    k_init<<<128, 256, 0, stream>>>(M0, W1, bM0, b1, cnt8, M / 4, WPhi, WPlo, bias192);
    k_pre<<<npre, 256, 0, stream>>>(x, W0, b0, WPhi, WPlo, bias192,
                                    zb, PQ, Pp, N, ei, cnt8, E);
    k_scan1<<<NB, 256, 0, stream>>>(cnt8, rs8f, bsum, M);
    k_scan_add<<<(M + 255) / 256, 256, 0, stream>>>(rs8f, cur8, bsum, NB, M, E);
    k_scatter8<<<1600, 256, 0, stream>>>(ei, cur8, csr8, E, N);
    k_final<<<2048, 256, 0, stream>>>(zb, PQ, Pp, rs8f, csr8, W2, b2, out, N);
}

// Round 12
// 161.661 us; speedup vs baseline: 1.2367x; 1.2367x over previous
//
#include <hip/hip_runtime.h>

#define HID 64
#define IN_C 16

typedef __attribute__((ext_vector_type(8))) short short8;
typedef __attribute__((ext_vector_type(4))) float f32x4;

__device__ __forceinline__ float bitsf(unsigned u) { return __uint_as_float(u); }
__device__ __forceinline__ float lanebcf(float v, int l) {
    return __int_as_float(__builtin_amdgcn_readlane(__float_as_int(v), l));
}
__device__ __forceinline__ float f4c(const float4& a, int c) {
    switch (c & 3) { case 0: return a.x; case 1: return a.y; case 2: return a.z; default: return a.w; }
}

// ---- k_init: zero cnt8 + pack stacked weights [WZ | W1+WQ | W1] into MFMA B-frags ----
// WZ = Mt@W1 (bias 0), WPQ = W1 + Mb@W1 (bias b1 + bM0@W1), P-tile = W1 (bias b1).
__global__ void k_init(const float* __restrict__ M0, const float* __restrict__ W1,
                       const float* __restrict__ bM0, const float* __restrict__ b1,
                       int* __restrict__ cnt8, int M4,
                       ushort* __restrict__ WPhi, ushort* __restrict__ WPlo,
                       float* __restrict__ bias192) {
    int tid = blockIdx.x * 256 + threadIdx.x;
    int stride = gridDim.x * 256;
    int4 z4 = {0, 0, 0, 0};
    for (int i = tid; i < M4; i += stride) reinterpret_cast<int4*>(cnt8)[i] = z4;

    if (tid < 64 * 192) {
        int cc = tid % 192;
        int k  = tid / 192;
        float w;
        if (cc < 64) {
            float a = 0.f;
#pragma unroll
            for (int m = 0; m < HID; ++m) a = fmaf(M0[k * HID + m], W1[m * HID + cc], a);
            w = a;
        } else if (cc < 128) {
            int c = cc - 64;
            float a = W1[k * HID + c];
#pragma unroll
            for (int m = 0; m < HID; ++m) a = fmaf(M0[(HID + k) * HID + m], W1[m * HID + c], a);
            w = a;
        } else {
            w = W1[k * HID + (cc - 128)];
        }
        unsigned wb = __float_as_uint(w);
        ushort hi = (ushort)(wb >> 16);
        float hif = __uint_as_float(wb & 0xffff0000u);
        ushort lo = (ushort)(__float_as_uint(w - hif) >> 16);
        int ct = cc >> 4, s = k >> 5, l = ((k >> 3) & 3) * 16 + (cc & 15), j = k & 7;
        int fi = ((ct * 2 + s) * 64 + l) * 8 + j;
        WPhi[fi] = hi;
        WPlo[fi] = lo;
        if (k == 0) {
            float bv;
            if (cc < 64) bv = 0.f;
            else if (cc < 128) {
                int c = cc - 64;
                float a = b1[c];
#pragma unroll
                for (int m = 0; m < HID; ++m) a = fmaf(bM0[m], W1[m * HID + c], a);
                bv = a;
            } else bv = b1[cc - 128];
            bias192[cc] = bv;
        }
    }
}

// ---- standalone per-XCD histogram with rank capture, 8-deep batched atomics ----
__global__ void k_hist(const int* __restrict__ ei, int* __restrict__ cnt8,
                       int* __restrict__ rank, int E, int N) {
    int xcd = blockIdx.x & 7;
    int o   = blockIdx.x >> 3;
    int Sx  = gridDim.x >> 3;
    int CH  = (E + 7) / 8;
    int e0  = xcd * CH;
    int e1  = min(e0 + CH, E);
    int* cx = cnt8 + (size_t)xcd * N;
    int step = Sx * 256;
    for (int base = e0 + o * 256 + (int)threadIdx.x; base < e1; base += step * 8) {
        int dsts[8];
        int cnt = 0;
#pragma unroll
        for (int u = 0; u < 8; ++u) {
            int e = base + u * step;
            if (e < e1) { dsts[u] = ei[E + e]; cnt = u + 1; }
        }
        int pos[8];
#pragma unroll
        for (int u = 0; u < 8; ++u)
            if (u < cnt) pos[u] = atomicAdd(&cx[dsts[u]], 1);
#pragma unroll
        for (int u = 0; u < 8; ++u)
            if (u < cnt) rank[base + u * step] = pos[u];
    }
}

// ---- pure MFMA precompute: h=relu(x@W0+b0); [zb(bf16) | PQ | Pp] = h @ Wstack + bias ----
__global__ __launch_bounds__(256) void k_pre(
    const float* __restrict__ x, const float* __restrict__ W0, const float* __restrict__ b0,
    const ushort* __restrict__ WPhi, const ushort* __restrict__ WPlo,
    const float* __restrict__ bias192,
    ushort* __restrict__ zb, float* __restrict__ PQ, float* __restrict__ Pp, int N)
{
    __shared__ ushort hhi[64 * 64];
    __shared__ ushort hlo[64 * 64];

    int tid  = threadIdx.x;
    int lane = tid & 63;
    int w    = tid >> 6;
    int n0   = blockIdx.x * 64;

    float w0c[IN_C];
#pragma unroll
    for (int k = 0; k < IN_C; ++k) w0c[k] = W0[k * HID + lane];
    float b0l = b0[lane];

    short8 Bhi[3][2], Blo[3][2];
    float bias[3];
#pragma unroll
    for (int i = 0; i < 3; ++i) {
        int ct = w * 3 + i;
#pragma unroll
        for (int s = 0; s < 2; ++s) {
            int fi = ((ct * 2 + s) * 64 + lane) * 8;
            Bhi[i][s] = *reinterpret_cast<const short8*>(WPhi + fi);
            Blo[i][s] = *reinterpret_cast<const short8*>(WPlo + fi);
        }
        bias[i] = bias192[ct * 16 + (lane & 15)];
    }

    int nx = n0 + w * 16 + (lane >> 2);
    float4 xq = make_float4(0.f, 0.f, 0.f, 0.f);
    if (nx < N) xq = *reinterpret_cast<const float4*>(x + (size_t)nx * IN_C + (lane & 3) * 4);

    // --- phase 1: wave-parallel x -> h (16 nodes/wave), split bf16, swizzled LDS ---
#pragma unroll
    for (int nn = 0; nn < 16; ++nn) {
        float acc = b0l;
#pragma unroll
        for (int k = 0; k < IN_C; ++k)
            acc = fmaf(lanebcf(f4c(xq, k & 3), 4 * nn + (k >> 2)), w0c[k], acc);
        float h = fmaxf(acc, 0.f);
        unsigned hb = __float_as_uint(h);
        ushort hi = (ushort)(hb >> 16);
        float hif = __uint_as_float(hb & 0xffff0000u);
        ushort lo = (ushort)(__float_as_uint(h - hif) >> 16);
        int nl = w * 16 + nn;
        int u  = ((lane >> 3) ^ (nl & 7));
        int off = nl * 64 + u * 8 + (lane & 7);
        hhi[off] = hi;
        hlo[off] = lo;
    }
    __syncthreads();

    // --- phase 2: MFMA ---
#pragma unroll
    for (int st = 0; st < 4; ++st) {
        int nloc = st * 16 + (lane & 15);
        short8 Ahi[2], Alo[2];
#pragma unroll
        for (int s = 0; s < 2; ++s) {
            int u = (s * 4 + (lane >> 4)) ^ (nloc & 7);
            int off = nloc * 64 + u * 8;
            Ahi[s] = *reinterpret_cast<const short8*>(hhi + off);
            Alo[s] = *reinterpret_cast<const short8*>(hlo + off);
        }
#pragma unroll
        for (int i = 0; i < 3; ++i) {
            int ct = w * 3 + i;
            f32x4 acc = {bias[i], bias[i], bias[i], bias[i]};
#pragma unroll
            for (int s = 0; s < 2; ++s) {
                acc = __builtin_amdgcn_mfma_f32_16x16x32_bf16(Ahi[s], Bhi[i][s], acc, 0, 0, 0);
                acc = __builtin_amdgcn_mfma_f32_16x16x32_bf16(Ahi[s], Blo[i][s], acc, 0, 0, 0);
                acc = __builtin_amdgcn_mfma_f32_16x16x32_bf16(Alo[s], Bhi[i][s], acc, 0, 0, 0);
                acc = __builtin_amdgcn_mfma_f32_16x16x32_bf16(Alo[s], Blo[i][s], acc, 0, 0, 0);
            }
            int ch = ct * 16 + (lane & 15);
#pragma unroll
            for (int r = 0; r < 4; ++r) {
                int n = n0 + st * 16 + (lane >> 4) * 4 + r;
                if (n >= N) continue;
                float v = acc[r];
                if (ch < 64) {
                    unsigned u = __float_as_uint(v);
                    unsigned rr = (u + 0x7fffu + ((u >> 16) & 1u)) >> 16;
                    zb[(size_t)n * HID + ch] = (ushort)rr;
                } else if (ch < 128) {
                    PQ[(size_t)n * HID + (ch - 64)] = v;
                } else {
                    Pp[(size_t)n * HID + (ch - 128)] = v;
                }
            }
        }
    }
}

// ---- exclusive scan over M=8N elements, 16 per thread (4096/block) ----
__global__ void k_scan1(const int* __restrict__ cnt, int* __restrict__ rs,
                        int* __restrict__ bsum, int M) {
    __shared__ int lds[256];
    int t = threadIdx.x;
    int base = blockIdx.x * 4096 + t * 16;
    int v[16];
    if (base + 16 <= M) {
#pragma unroll
        for (int u = 0; u < 4; ++u) {
            int4 w = *reinterpret_cast<const int4*>(cnt + base + u * 4);
            v[u * 4 + 0] = w.x; v[u * 4 + 1] = w.y; v[u * 4 + 2] = w.z; v[u * 4 + 3] = w.w;
        }
    } else {
#pragma unroll
        for (int u = 0; u < 16; ++u) v[u] = (base + u < M) ? cnt[base + u] : 0;
    }
    int run = 0;
#pragma unroll
    for (int u = 0; u < 16; ++u) { int tv = v[u]; v[u] = run; run += tv; }
    lds[t] = run;
    __syncthreads();
#pragma unroll
    for (int off = 1; off < 256; off <<= 1) {
        int xw = (t >= off) ? lds[t - off] : 0;
        __syncthreads();
        lds[t] += xw;
        __syncthreads();
    }
    int excl = lds[t] - run;
    if (t == 255) bsum[blockIdx.x] = lds[255];
#pragma unroll
    for (int u = 0; u < 16; ++u)
        if (base + u < M) rs[base + u] = excl + v[u];
}

// rs[i] += exscan(bsum)[i>>12]; rs[M]=E
__global__ void k_scan_add(int* __restrict__ rs, const int* __restrict__ bsum,
                           int NB, int M, int E) {
    __shared__ int lds[256];
    __shared__ int excl[256];
    int t = threadIdx.x;
    int v = (t < NB) ? bsum[t] : 0;
    lds[t] = v;
    __syncthreads();
#pragma unroll
    for (int off = 1; off < 256; off <<= 1) {
        int xw = (t >= off) ? lds[t - off] : 0;
        __syncthreads();
        lds[t] += xw;
        __syncthreads();
    }
    excl[t] = lds[t] - v;
    __syncthreads();
    int i = blockIdx.x * 256 + t;
    if (i < M) rs[i] += excl[i >> 12];
    if (i == 0) rs[M] = E;
}

// ---- atomic-free scatter: csr8[rs[dst] + rank[e]] = src (XCD-local) ----
__global__ void k_scatter_r(const int* __restrict__ ei, const int* __restrict__ rank,
                            const int* __restrict__ rs8f, int* __restrict__ csr8,
                            int E, int N) {
    int xcd = blockIdx.x & 7;
    int o   = blockIdx.x >> 3;
    int Sx  = gridDim.x >> 3;
    int CH  = (E + 7) / 8;
    int e0  = xcd * CH;
    int e1  = min(e0 + CH, E);
    const int* rx = rs8f + (size_t)xcd * N;
    for (int e = e0 + o * 256 + (int)threadIdx.x; e < e1; e += Sx * 256) {
        int srcn = ei[e];
        int dstn = ei[E + e];
        csr8[rx[dstn] + rank[e]] = srcn;
    }
}

// ---- bf16 gather (2 edges/round per 16-lane group) + elementwise epilogue ----
__global__ __launch_bounds__(256) void k_final(
    const ushort* __restrict__ zb, const float* __restrict__ PQ, const float* __restrict__ Pp,
    const int* __restrict__ rs8f, const int* __restrict__ csr8,
    const float* __restrict__ W2, const float* __restrict__ b2,
    float* __restrict__ out, int N)
{
    int lane = threadIdx.x & 63;
    int g    = lane >> 4;
    int ql   = lane & 15;
    int oct  = ql & 7;
    int half = ql >> 3;
    int wid  = (blockIdx.x * 256 + threadIdx.x) >> 6;
    int nw   = (gridDim.x * 256) >> 6;

    int c0 = oct * 8 + half * 4;
    float4 w2v = *reinterpret_cast<const float4*>(W2 + c0);
    float b2s = b2[0];

    for (int n0 = wid * 4; n0 < N; n0 += nw * 4) {
        int ng   = n0 + g;
        bool okg = ng < N;

        int rv = okg ? rs8f[(size_t)oct * N + ng + half] : 0;
        int bx[8], cum[8];
        int dsum = 0;
#pragma unroll
        for (int xx = 0; xx < 8; ++xx) {
            int bb = __shfl(rv, g * 16 + xx);
            int ee = __shfl(rv, g * 16 + 8 + xx);
            bx[xx] = bb;
            cum[xx] = dsum;
            dsum += (ee - bb);
        }
        int deg = dsum;
        int md = deg;
        md = max(md, __shfl_xor(md, 16));
        md = max(md, __shfl_xor(md, 32));

        float acc[8];
#pragma unroll
        for (int i = 0; i < 8; ++i) acc[i] = 0.f;

        for (int c = 0; c < md; c += 32) {
            int j0 = c + ql, j1 = c + 16 + ql;
            int a0 = bx[0] + j0, a1 = bx[0] + j1;
#pragma unroll
            for (int xx = 1; xx < 8; ++xx) {
                a0 = (j0 >= cum[xx]) ? (bx[xx] + (j0 - cum[xx])) : a0;
                a1 = (j1 >= cum[xx]) ? (bx[xx] + (j1 - cum[xx])) : a1;
            }
            int ia = (j0 < deg) ? csr8[a0] : -1;
            int ib = (j1 < deg) ? csr8[a1] : -1;
#pragma unroll
            for (int tb = 0; tb < 4; ++tb) {
                if (tb > 0 && md <= c + 8 * tb) break;
                int srcs[4];
#pragma unroll
                for (int t4 = 0; t4 < 4; ++t4) {
                    int t = tb * 4 + t4;
                    int e = 2 * t + half;
                    srcs[t4] = __shfl(tb < 2 ? ia : ib, g * 16 + (e & 15));
                }
                uint4 rw[4];
#pragma unroll
                for (int t4 = 0; t4 < 4; ++t4) {
                    int s = srcs[t4] < 0 ? 0 : srcs[t4];
                    rw[t4] = *reinterpret_cast<const uint4*>(zb + (size_t)s * HID + oct * 8);
                }
#pragma unroll
                for (int t4 = 0; t4 < 4; ++t4) {
                    if (srcs[t4] >= 0) {
                        uint4 wv = rw[t4];
                        acc[0] += bitsf(wv.x << 16); acc[1] += bitsf(wv.x & 0xffff0000u);
                        acc[2] += bitsf(wv.y << 16); acc[3] += bitsf(wv.y & 0xffff0000u);
                        acc[4] += bitsf(wv.z << 16); acc[5] += bitsf(wv.z & 0xffff0000u);
                        acc[6] += bitsf(wv.w << 16); acc[7] += bitsf(wv.w & 0xffff0000u);
                    }
                }
            }
        }
#pragma unroll
        for (int i = 0; i < 8; ++i) acc[i] += __shfl_xor(acc[i], 8);

        float s0 = half ? acc[4] : acc[0];
        float s1 = half ? acc[5] : acc[1];
        float s2 = half ? acc[6] : acc[2];
        float s3 = half ? acc[7] : acc[3];

        float4 base = make_float4(0.f, 0.f, 0.f, 0.f);
        if (okg) {
            base = *reinterpret_cast<const float4*>(PQ + (size_t)ng * HID + c0);
            if (deg == 0)
                base = *reinterpret_cast<const float4*>(Pp + (size_t)ng * HID + c0);
        }
        float rcpd = (deg > 0) ? (1.f / (float)deg) : 0.f;
        float y0 = base.x + s0 * rcpd;
        float y1 = base.y + s1 * rcpd;
        float y2 = base.z + s2 * rcpd;
        float y3 = base.w + s3 * rcpd;

        float part = fmaxf(y0, 0.f) * w2v.x + fmaxf(y1, 0.f) * w2v.y +
                     fmaxf(y2, 0.f) * w2v.z + fmaxf(y3, 0.f) * w2v.w;
#pragma unroll
        for (int off = 1; off < 16; off <<= 1) part += __shfl_xor(part, off);
        if (ql == 0 && okg) out[ng] = part + b2s;
    }
}

extern "C" void kernel_launch(void* const* d_in, const int* in_sizes, int n_in,
                              void* d_out, int out_size, void* d_ws, size_t ws_size,
                              hipStream_t stream) {
    const float* x   = (const float*)d_in[0];
    const int*   ei  = (const int*)d_in[1];
    const float* W0  = (const float*)d_in[2];
    const float* b0  = (const float*)d_in[3];
    const float* W1  = (const float*)d_in[4];
    const float* b1  = (const float*)d_in[5];
    const float* W2  = (const float*)d_in[6];
    const float* b2  = (const float*)d_in[7];
    const float* M0  = (const float*)d_in[8];
    const float* bM0 = (const float*)d_in[9];

    int N = in_sizes[0] / IN_C;
    int E = in_sizes[1] / 2;
    int M = 8 * N;
    int NB = (M + 4095) / 4096;   // <= 256 for N <= 131072

    ushort* zb     = (ushort*)d_ws;                   // N*64 bf16
    float*  PQ     = (float*)(zb + (size_t)N * HID);  // N*64
    float*  Pp     = PQ + (size_t)N * HID;            // N*64
    ushort* WPhi   = (ushort*)(Pp + (size_t)N * HID); // 12288
    ushort* WPlo   = WPhi + 12288;                    // 12288
    float*  bias192= (float*)(WPlo + 12288);          // 192
    int*    cnt8   = (int*)(bias192 + 192);           // 8N
    int*    rs8f   = cnt8 + (size_t)M;                // 8N+1
    int*    bsum   = rs8f + (size_t)M + 1;            // 256
    int*    rank   = bsum + 256;                      // E
    int*    csr8   = rank + (size_t)E;                // E
    float*  out    = (float*)d_out;

    int npre = (N + 63) / 64;

    k_init<<<128, 256, 0, stream>>>(M0, W1, bM0, b1, cnt8, M / 4, WPhi, WPlo, bias192);
    k_hist<<<2048, 256, 0, stream>>>(ei, cnt8, rank, E, N);
    k_pre<<<npre, 256, 0, stream>>>(x, W0, b0, WPhi, WPlo, bias192, zb, PQ, Pp, N);
    k_scan1<<<NB, 256, 0, stream>>>(cnt8, rs8f, bsum, M);
    k_scan_add<<<(M + 255) / 256, 256, 0, stream>>>(rs8f, bsum, NB, M, E);
    k_scatter_r<<<1600, 256, 0, stream>>>(ei, rank, rs8f, csr8, E, N);
    k_final<<<2048, 256, 0, stream>>>(zb, PQ, Pp, rs8f, csr8, W2, b2, out, N);
}

// Round 13
// 157.922 us; speedup vs baseline: 1.2660x; 1.0237x over previous
//
#include <hip/hip_runtime.h>

#define HID 64
#define IN_C 16

typedef __attribute__((ext_vector_type(8))) short short8;
typedef __attribute__((ext_vector_type(4))) float f32x4;

__device__ __forceinline__ float bitsf(unsigned u) { return __uint_as_float(u); }
__device__ __forceinline__ float lanebcf(float v, int l) {
    return __int_as_float(__builtin_amdgcn_readlane(__float_as_int(v), l));
}
__device__ __forceinline__ float f4c(const float4& a, int c) {
    switch (c & 3) { case 0: return a.x; case 1: return a.y; case 2: return a.z; default: return a.w; }
}

// ---- k_init: zero cnt8 + pack stacked weights [WZ | W1+WQ | W1] into MFMA B-frags ----
__global__ void k_init(const float* __restrict__ M0, const float* __restrict__ W1,
                       const float* __restrict__ bM0, const float* __restrict__ b1,
                       int* __restrict__ cnt8, int M4,
                       ushort* __restrict__ WPhi, ushort* __restrict__ WPlo,
                       float* __restrict__ bias192) {
    int tid = blockIdx.x * 256 + threadIdx.x;
    int stride = gridDim.x * 256;
    int4 z4 = {0, 0, 0, 0};
    for (int i = tid; i < M4; i += stride) reinterpret_cast<int4*>(cnt8)[i] = z4;

    if (tid < 64 * 192) {
        int cc = tid % 192;
        int k  = tid / 192;
        float w;
        if (cc < 64) {
            float a = 0.f;
#pragma unroll
            for (int m = 0; m < HID; ++m) a = fmaf(M0[k * HID + m], W1[m * HID + cc], a);
            w = a;
        } else if (cc < 128) {
            int c = cc - 64;
            float a = W1[k * HID + c];
#pragma unroll
            for (int m = 0; m < HID; ++m) a = fmaf(M0[(HID + k) * HID + m], W1[m * HID + c], a);
            w = a;
        } else {
            w = W1[k * HID + (cc - 128)];
        }
        unsigned wb = __float_as_uint(w);
        ushort hi = (ushort)(wb >> 16);
        float hif = __uint_as_float(wb & 0xffff0000u);
        ushort lo = (ushort)(__float_as_uint(w - hif) >> 16);
        int ct = cc >> 4, s = k >> 5, l = ((k >> 3) & 3) * 16 + (cc & 15), j = k & 7;
        int fi = ((ct * 2 + s) * 64 + l) * 8 + j;
        WPhi[fi] = hi;
        WPlo[fi] = lo;
        if (k == 0) {
            float bv;
            if (cc < 64) bv = 0.f;
            else if (cc < 128) {
                int c = cc - 64;
                float a = b1[c];
#pragma unroll
                for (int m = 0; m < HID; ++m) a = fmaf(bM0[m], W1[m * HID + c], a);
                bv = a;
            } else bv = b1[cc - 128];
            bias192[cc] = bv;
        }
    }
}

// ---- role-split: blocks [0,nbh) = hist (atomic-pipe) ; [nbh,..) = MFMA pre (VALU/MFMA/BW) ----
__global__ __launch_bounds__(256) void k_pre_hist(
    const float* __restrict__ x, const float* __restrict__ W0, const float* __restrict__ b0,
    const ushort* __restrict__ WPhi, const ushort* __restrict__ WPlo,
    const float* __restrict__ bias192,
    ushort* __restrict__ zb, float* __restrict__ PQ, float* __restrict__ Pp, int N,
    const int* __restrict__ ei, int* __restrict__ cnt8, int* __restrict__ rank,
    int E, int nbh)
{
    __shared__ ushort hhi[64 * 64];
    __shared__ ushort hlo[64 * 64];

    if ((int)blockIdx.x < nbh) {
        // --- hist role: per-XCD, 8-deep batched rank-capturing atomics (r12 verbatim) ---
        int xcd = blockIdx.x & 7;
        int o   = blockIdx.x >> 3;
        int Sx  = nbh >> 3;
        int CH  = (E + 7) / 8;
        int e0  = xcd * CH;
        int e1  = min(e0 + CH, E);
        int* cx = cnt8 + (size_t)xcd * N;
        int step = Sx * 256;
        for (int base = e0 + o * 256 + (int)threadIdx.x; base < e1; base += step * 8) {
            int dsts[8];
            int cnt = 0;
#pragma unroll
            for (int u = 0; u < 8; ++u) {
                int e = base + u * step;
                if (e < e1) { dsts[u] = ei[E + e]; cnt = u + 1; }
            }
            int pos[8];
#pragma unroll
            for (int u = 0; u < 8; ++u)
                if (u < cnt) pos[u] = atomicAdd(&cx[dsts[u]], 1);
#pragma unroll
            for (int u = 0; u < 8; ++u)
                if (u < cnt) rank[base + u * step] = pos[u];
        }
        return;
    }

    int tid  = threadIdx.x;
    int lane = tid & 63;
    int w    = tid >> 6;
    int n0   = (blockIdx.x - nbh) * 64;

    float w0c[IN_C];
#pragma unroll
    for (int k = 0; k < IN_C; ++k) w0c[k] = W0[k * HID + lane];
    float b0l = b0[lane];

    short8 Bhi[3][2], Blo[3][2];
    float bias[3];
#pragma unroll
    for (int i = 0; i < 3; ++i) {
        int ct = w * 3 + i;
#pragma unroll
        for (int s = 0; s < 2; ++s) {
            int fi = ((ct * 2 + s) * 64 + lane) * 8;
            Bhi[i][s] = *reinterpret_cast<const short8*>(WPhi + fi);
            Blo[i][s] = *reinterpret_cast<const short8*>(WPlo + fi);
        }
        bias[i] = bias192[ct * 16 + (lane & 15)];
    }

    int nx = n0 + w * 16 + (lane >> 2);
    float4 xq = make_float4(0.f, 0.f, 0.f, 0.f);
    if (nx < N) xq = *reinterpret_cast<const float4*>(x + (size_t)nx * IN_C + (lane & 3) * 4);

    // --- phase 1: wave-parallel x -> h (16 nodes/wave), split bf16, swizzled LDS ---
#pragma unroll
    for (int nn = 0; nn < 16; ++nn) {
        float acc = b0l;
#pragma unroll
        for (int k = 0; k < IN_C; ++k)
            acc = fmaf(lanebcf(f4c(xq, k & 3), 4 * nn + (k >> 2)), w0c[k], acc);
        float h = fmaxf(acc, 0.f);
        unsigned hb = __float_as_uint(h);
        ushort hi = (ushort)(hb >> 16);
        float hif = __uint_as_float(hb & 0xffff0000u);
        ushort lo = (ushort)(__float_as_uint(h - hif) >> 16);
        int nl = w * 16 + nn;
        int u  = ((lane >> 3) ^ (nl & 7));
        int off = nl * 64 + u * 8 + (lane & 7);
        hhi[off] = hi;
        hlo[off] = lo;
    }
    __syncthreads();

    // --- phase 2: MFMA ---
#pragma unroll
    for (int st = 0; st < 4; ++st) {
        int nloc = st * 16 + (lane & 15);
        short8 Ahi[2], Alo[2];
#pragma unroll
        for (int s = 0; s < 2; ++s) {
            int u = (s * 4 + (lane >> 4)) ^ (nloc & 7);
            int off = nloc * 64 + u * 8;
            Ahi[s] = *reinterpret_cast<const short8*>(hhi + off);
            Alo[s] = *reinterpret_cast<const short8*>(hlo + off);
        }
#pragma unroll
        for (int i = 0; i < 3; ++i) {
            int ct = w * 3 + i;
            f32x4 acc = {bias[i], bias[i], bias[i], bias[i]};
#pragma unroll
            for (int s = 0; s < 2; ++s) {
                acc = __builtin_amdgcn_mfma_f32_16x16x32_bf16(Ahi[s], Bhi[i][s], acc, 0, 0, 0);
                acc = __builtin_amdgcn_mfma_f32_16x16x32_bf16(Ahi[s], Blo[i][s], acc, 0, 0, 0);
                acc = __builtin_amdgcn_mfma_f32_16x16x32_bf16(Alo[s], Bhi[i][s], acc, 0, 0, 0);
                acc = __builtin_amdgcn_mfma_f32_16x16x32_bf16(Alo[s], Blo[i][s], acc, 0, 0, 0);
            }
            int ch = ct * 16 + (lane & 15);
#pragma unroll
            for (int r = 0; r < 4; ++r) {
                int n = n0 + st * 16 + (lane >> 4) * 4 + r;
                if (n >= N) continue;
                float v = acc[r];
                if (ch < 64) {
                    unsigned u = __float_as_uint(v);
                    unsigned rr = (u + 0x7fffu + ((u >> 16) & 1u)) >> 16;
                    zb[(size_t)n * HID + ch] = (ushort)rr;
                } else if (ch < 128) {
                    PQ[(size_t)n * HID + (ch - 64)] = v;
                } else {
                    Pp[(size_t)n * HID + (ch - 128)] = v;
                }
            }
        }
    }
}

// ---- exclusive scan over M=8N elements, 16 per thread (4096/block) ----
__global__ void k_scan1(const int* __restrict__ cnt, int* __restrict__ rs,
                        int* __restrict__ bsum, int M) {
    __shared__ int lds[256];
    int t = threadIdx.x;
    int base = blockIdx.x * 4096 + t * 16;
    int v[16];
    if (base + 16 <= M) {
#pragma unroll
        for (int u = 0; u < 4; ++u) {
            int4 w = *reinterpret_cast<const int4*>(cnt + base + u * 4);
            v[u * 4 + 0] = w.x; v[u * 4 + 1] = w.y; v[u * 4 + 2] = w.z; v[u * 4 + 3] = w.w;
        }
    } else {
#pragma unroll
        for (int u = 0; u < 16; ++u) v[u] = (base + u < M) ? cnt[base + u] : 0;
    }
    int run = 0;
#pragma unroll
    for (int u = 0; u < 16; ++u) { int tv = v[u]; v[u] = run; run += tv; }
    lds[t] = run;
    __syncthreads();
#pragma unroll
    for (int off = 1; off < 256; off <<= 1) {
        int xw = (t >= off) ? lds[t - off] : 0;
        __syncthreads();
        lds[t] += xw;
        __syncthreads();
    }
    int excl = lds[t] - run;
    if (t == 255) bsum[blockIdx.x] = lds[255];
#pragma unroll
    for (int u = 0; u < 16; ++u)
        if (base + u < M) rs[base + u] = excl + v[u];
}

// rs[i] += exscan(bsum)[i>>12]; rs[M]=E
__global__ void k_scan_add(int* __restrict__ rs, const int* __restrict__ bsum,
                           int NB, int M, int E) {
    __shared__ int lds[256];
    __shared__ int excl[256];
    int t = threadIdx.x;
    int v = (t < NB) ? bsum[t] : 0;
    lds[t] = v;
    __syncthreads();
#pragma unroll
    for (int off = 1; off < 256; off <<= 1) {
        int xw = (t >= off) ? lds[t - off] : 0;
        __syncthreads();
        lds[t] += xw;
        __syncthreads();
    }
    excl[t] = lds[t] - v;
    __syncthreads();
    int i = blockIdx.x * 256 + t;
    if (i < M) rs[i] += excl[i >> 12];
    if (i == 0) rs[M] = E;
}

// ---- atomic-free scatter: csr8[rs[dst] + rank[e]] = src (XCD-local) ----
__global__ void k_scatter_r(const int* __restrict__ ei, const int* __restrict__ rank,
                            const int* __restrict__ rs8f, int* __restrict__ csr8,
                            int E, int N) {
    int xcd = blockIdx.x & 7;
    int o   = blockIdx.x >> 3;
    int Sx  = gridDim.x >> 3;
    int CH  = (E + 7) / 8;
    int e0  = xcd * CH;
    int e1  = min(e0 + CH, E);
    const int* rx = rs8f + (size_t)xcd * N;
    for (int e = e0 + o * 256 + (int)threadIdx.x; e < e1; e += Sx * 256) {
        int srcn = ei[e];
        int dstn = ei[E + e];
        csr8[rx[dstn] + rank[e]] = srcn;
    }
}

// ---- bf16 gather (2 edges/round per 16-lane group) + elementwise epilogue ----
__global__ __launch_bounds__(256) void k_final(
    const ushort* __restrict__ zb, const float* __restrict__ PQ, const float* __restrict__ Pp,
    const int* __restrict__ rs8f, const int* __restrict__ csr8,
    const float* __restrict__ W2, const float* __restrict__ b2,
    float* __restrict__ out, int N)
{
    int lane = threadIdx.x & 63;
    int g    = lane >> 4;
    int ql   = lane & 15;
    int oct  = ql & 7;
    int half = ql >> 3;
    int wid  = (blockIdx.x * 256 + threadIdx.x) >> 6;
    int nw   = (gridDim.x * 256) >> 6;

    int c0 = oct * 8 + half * 4;
    float4 w2v = *reinterpret_cast<const float4*>(W2 + c0);
    float b2s = b2[0];

    for (int n0 = wid * 4; n0 < N; n0 += nw * 4) {
        int ng   = n0 + g;
        bool okg = ng < N;

        int rv = okg ? rs8f[(size_t)oct * N + ng + half] : 0;
        int bx[8], cum[8];
        int dsum = 0;
#pragma unroll
        for (int xx = 0; xx < 8; ++xx) {
            int bb = __shfl(rv, g * 16 + xx);
            int ee = __shfl(rv, g * 16 + 8 + xx);
            bx[xx] = bb;
            cum[xx] = dsum;
            dsum += (ee - bb);
        }
        int deg = dsum;
        int md = deg;
        md = max(md, __shfl_xor(md, 16));
        md = max(md, __shfl_xor(md, 32));

        float acc[8];
#pragma unroll
        for (int i = 0; i < 8; ++i) acc[i] = 0.f;

        for (int c = 0; c < md; c += 32) {
            int j0 = c + ql, j1 = c + 16 + ql;
            int a0 = bx[0] + j0, a1 = bx[0] + j1;
#pragma unroll
            for (int xx = 1; xx < 8; ++xx) {
                a0 = (j0 >= cum[xx]) ? (bx[xx] + (j0 - cum[xx])) : a0;
                a1 = (j1 >= cum[xx]) ? (bx[xx] + (j1 - cum[xx])) : a1;
            }
            int ia = (j0 < deg) ? csr8[a0] : -1;
            int ib = (j1 < deg) ? csr8[a1] : -1;
#pragma unroll
            for (int tb = 0; tb < 4; ++tb) {
                if (tb > 0 && md <= c + 8 * tb) break;
                int srcs[4];
#pragma unroll
                for (int t4 = 0; t4 < 4; ++t4) {
                    int t = tb * 4 + t4;
                    int e = 2 * t + half;
                    srcs[t4] = __shfl(tb < 2 ? ia : ib, g * 16 + (e & 15));
                }
                uint4 rw[4];
#pragma unroll
                for (int t4 = 0; t4 < 4; ++t4) {
                    int s = srcs[t4] < 0 ? 0 : srcs[t4];
                    rw[t4] = *reinterpret_cast<const uint4*>(zb + (size_t)s * HID + oct * 8);
                }
#pragma unroll
                for (int t4 = 0; t4 < 4; ++t4) {
                    if (srcs[t4] >= 0) {
                        uint4 wv = rw[t4];
                        acc[0] += bitsf(wv.x << 16); acc[1] += bitsf(wv.x & 0xffff0000u);
                        acc[2] += bitsf(wv.y << 16); acc[3] += bitsf(wv.y & 0xffff0000u);
                        acc[4] += bitsf(wv.z << 16); acc[5] += bitsf(wv.z & 0xffff0000u);
                        acc[6] += bitsf(wv.w << 16); acc[7] += bitsf(wv.w & 0xffff0000u);
                    }
                }
            }
        }
#pragma unroll
        for (int i = 0; i < 8; ++i) acc[i] += __shfl_xor(acc[i], 8);

        float s0 = half ? acc[4] : acc[0];
        float s1 = half ? acc[5] : acc[1];
        float s2 = half ? acc[6] : acc[2];
        float s3 = half ? acc[7] : acc[3];

        float4 base = make_float4(0.f, 0.f, 0.f, 0.f);
        if (okg) {
            base = *reinterpret_cast<const float4*>(PQ + (size_t)ng * HID + c0);
            if (deg == 0)
                base = *reinterpret_cast<const float4*>(Pp + (size_t)ng * HID + c0);
        }
        float rcpd = (deg > 0) ? (1.f / (float)deg) : 0.f;
        float y0 = base.x + s0 * rcpd;
        float y1 = base.y + s1 * rcpd;
        float y2 = base.z + s2 * rcpd;
        float y3 = base.w + s3 * rcpd;

        float part = fmaxf(y0, 0.f) * w2v.x + fmaxf(y1, 0.f) * w2v.y +
                     fmaxf(y2, 0.f) * w2v.z + fmaxf(y3, 0.f) * w2v.w;
#pragma unroll
        for (int off = 1; off < 16; off <<= 1) part += __shfl_xor(part, off);
        if (ql == 0 && okg) out[ng] = part + b2s;
    }
}

extern "C" void kernel_launch(void* const* d_in, const int* in_sizes, int n_in,
                              void* d_out, int out_size, void* d_ws, size_t ws_size,
                              hipStream_t stream) {
    const float* x   = (const float*)d_in[0];
    const int*   ei  = (const int*)d_in[1];
    const float* W0  = (const float*)d_in[2];
    const float* b0  = (const float*)d_in[3];
    const float* W1  = (const float*)d_in[4];
    const float* b1  = (const float*)d_in[5];
    const float* W2  = (const float*)d_in[6];
    const float* b2  = (const float*)d_in[7];
    const float* M0  = (const float*)d_in[8];
    const float* bM0 = (const float*)d_in[9];

    int N = in_sizes[0] / IN_C;
    int E = in_sizes[1] / 2;
    int M = 8 * N;
    int NB = (M + 4095) / 4096;   // <= 256 for N <= 131072

    ushort* zb     = (ushort*)d_ws;                   // N*64 bf16
    float*  PQ     = (float*)(zb + (size_t)N * HID);  // N*64
    float*  Pp     = PQ + (size_t)N * HID;            // N*64
    ushort* WPhi   = (ushort*)(Pp + (size_t)N * HID); // 12288
    ushort* WPlo   = WPhi + 12288;                    // 12288
    float*  bias192= (float*)(WPlo + 12288);          // 192
    int*    cnt8   = (int*)(bias192 + 192);           // 8N
    int*    rs8f   = cnt8 + (size_t)M;                // 8N+1
    int*    bsum   = rs8f + (size_t)M + 1;            // 256
    int*    rank   = bsum + 256;                      // E
    int*    csr8   = rank + (size_t)E;                // E
    float*  out    = (float*)d_out;

    int nbh  = 2048;
    int npre = (N + 63) / 64;

    k_init<<<128, 256, 0, stream>>>(M0, W1, bM0, b1, cnt8, M / 4, WPhi, WPlo, bias192);
    k_pre_hist<<<nbh + npre, 256, 0, stream>>>(x, W0, b0, WPhi, WPlo, bias192,
                                               zb, PQ, Pp, N, ei, cnt8, rank, E, nbh);
    k_scan1<<<NB, 256, 0, stream>>>(cnt8, rs8f, bsum, M);
    k_scan_add<<<(M + 255) / 256, 256, 0, stream>>>(rs8f, bsum, NB, M, E);
    k_scatter_r<<<1600, 256, 0, stream>>>(ei, rank, rs8f, csr8, E, N);
    k_final<<<2048, 256, 0, stream>>>(zb, PQ, Pp, rs8f, csr8, W2, b2, out, N);
}

// Round 14
// 112.152 us; speedup vs baseline: 1.7826x; 1.4081x over previous
//
#include <hip/hip_runtime.h>

#define HID 64
#define IN_C 16

typedef __attribute__((ext_vector_type(8))) short short8;
typedef __attribute__((ext_vector_type(4))) float f32x4;

__device__ __forceinline__ float bitsf(unsigned u) { return __uint_as_float(u); }
__device__ __forceinline__ float lanebcf(float v, int l) {
    return __int_as_float(__builtin_amdgcn_readlane(__float_as_int(v), l));
}
__device__ __forceinline__ float f4c(const float4& a, int c) {
    switch (c & 3) { case 0: return a.x; case 1: return a.y; case 2: return a.z; default: return a.w; }
}

// ---- k_init: pack stacked weights [WZ | W1+WQ | W1] into MFMA B-frags (no zeroing needed) ----
__global__ void k_init(const float* __restrict__ M0, const float* __restrict__ W1,
                       const float* __restrict__ bM0, const float* __restrict__ b1,
                       ushort* __restrict__ WPhi, ushort* __restrict__ WPlo,
                       float* __restrict__ bias192) {
    int tid = blockIdx.x * 256 + threadIdx.x;
    if (tid >= 64 * 192) return;
    int cc = tid % 192;
    int k  = tid / 192;
    float w;
    if (cc < 64) {
        float a = 0.f;
#pragma unroll
        for (int m = 0; m < HID; ++m) a = fmaf(M0[k * HID + m], W1[m * HID + cc], a);
        w = a;
    } else if (cc < 128) {
        int c = cc - 64;
        float a = W1[k * HID + c];
#pragma unroll
        for (int m = 0; m < HID; ++m) a = fmaf(M0[(HID + k) * HID + m], W1[m * HID + c], a);
        w = a;
    } else {
        w = W1[k * HID + (cc - 128)];
    }
    unsigned wb = __float_as_uint(w);
    ushort hi = (ushort)(wb >> 16);
    float hif = __uint_as_float(wb & 0xffff0000u);
    ushort lo = (ushort)(__float_as_uint(w - hif) >> 16);
    int ct = cc >> 4, s = k >> 5, l = ((k >> 3) & 3) * 16 + (cc & 15), j = k & 7;
    int fi = ((ct * 2 + s) * 64 + l) * 8 + j;
    WPhi[fi] = hi;
    WPlo[fi] = lo;
    if (k == 0) {
        float bv;
        if (cc < 64) bv = 0.f;
        else if (cc < 128) {
            int c = cc - 64;
            float a = b1[c];
#pragma unroll
            for (int m = 0; m < HID; ++m) a = fmaf(bM0[m], W1[m * HID + c], a);
            bv = a;
        } else bv = b1[cc - 128];
        bias192[cc] = bv;
    }
}

// ---- pure MFMA precompute: h=relu(x@W0+b0); [zb(bf16) | PQ | Pp] = h @ Wstack + bias ----
__global__ __launch_bounds__(256) void k_pre(
    const float* __restrict__ x, const float* __restrict__ W0, const float* __restrict__ b0,
    const ushort* __restrict__ WPhi, const ushort* __restrict__ WPlo,
    const float* __restrict__ bias192,
    ushort* __restrict__ zb, float* __restrict__ PQ, float* __restrict__ Pp, int N)
{
    __shared__ ushort hhi[64 * 64];
    __shared__ ushort hlo[64 * 64];

    int tid  = threadIdx.x;
    int lane = tid & 63;
    int w    = tid >> 6;
    int n0   = blockIdx.x * 64;

    float w0c[IN_C];
#pragma unroll
    for (int k = 0; k < IN_C; ++k) w0c[k] = W0[k * HID + lane];
    float b0l = b0[lane];

    short8 Bhi[3][2], Blo[3][2];
    float bias[3];
#pragma unroll
    for (int i = 0; i < 3; ++i) {
        int ct = w * 3 + i;
#pragma unroll
        for (int s = 0; s < 2; ++s) {
            int fi = ((ct * 2 + s) * 64 + lane) * 8;
            Bhi[i][s] = *reinterpret_cast<const short8*>(WPhi + fi);
            Blo[i][s] = *reinterpret_cast<const short8*>(WPlo + fi);
        }
        bias[i] = bias192[ct * 16 + (lane & 15)];
    }

    int nx = n0 + w * 16 + (lane >> 2);
    float4 xq = make_float4(0.f, 0.f, 0.f, 0.f);
    if (nx < N) xq = *reinterpret_cast<const float4*>(x + (size_t)nx * IN_C + (lane & 3) * 4);

#pragma unroll
    for (int nn = 0; nn < 16; ++nn) {
        float acc = b0l;
#pragma unroll
        for (int k = 0; k < IN_C; ++k)
            acc = fmaf(lanebcf(f4c(xq, k & 3), 4 * nn + (k >> 2)), w0c[k], acc);
        float h = fmaxf(acc, 0.f);
        unsigned hb = __float_as_uint(h);
        ushort hi = (ushort)(hb >> 16);
        float hif = __uint_as_float(hb & 0xffff0000u);
        ushort lo = (ushort)(__float_as_uint(h - hif) >> 16);
        int nl = w * 16 + nn;
        int u  = ((lane >> 3) ^ (nl & 7));
        int off = nl * 64 + u * 8 + (lane & 7);
        hhi[off] = hi;
        hlo[off] = lo;
    }
    __syncthreads();

#pragma unroll
    for (int st = 0; st < 4; ++st) {
        int nloc = st * 16 + (lane & 15);
        short8 Ahi[2], Alo[2];
#pragma unroll
        for (int s = 0; s < 2; ++s) {
            int u = (s * 4 + (lane >> 4)) ^ (nloc & 7);
            int off = nloc * 64 + u * 8;
            Ahi[s] = *reinterpret_cast<const short8*>(hhi + off);
            Alo[s] = *reinterpret_cast<const short8*>(hlo + off);
        }
#pragma unroll
        for (int i = 0; i < 3; ++i) {
            int ct = w * 3 + i;
            f32x4 acc = {bias[i], bias[i], bias[i], bias[i]};
#pragma unroll
            for (int s = 0; s < 2; ++s) {
                acc = __builtin_amdgcn_mfma_f32_16x16x32_bf16(Ahi[s], Bhi[i][s], acc, 0, 0, 0);
                acc = __builtin_amdgcn_mfma_f32_16x16x32_bf16(Ahi[s], Blo[i][s], acc, 0, 0, 0);
                acc = __builtin_amdgcn_mfma_f32_16x16x32_bf16(Alo[s], Bhi[i][s], acc, 0, 0, 0);
                acc = __builtin_amdgcn_mfma_f32_16x16x32_bf16(Alo[s], Blo[i][s], acc, 0, 0, 0);
            }
            int ch = ct * 16 + (lane & 15);
#pragma unroll
            for (int r = 0; r < 4; ++r) {
                int n = n0 + st * 16 + (lane >> 4) * 4 + r;
                if (n >= N) continue;
                float v = acc[r];
                if (ch < 64) {
                    unsigned u = __float_as_uint(v);
                    unsigned rr = (u + 0x7fffu + ((u >> 16) & 1u)) >> 16;
                    zb[(size_t)n * HID + ch] = (ushort)rr;
                } else if (ch < 128) {
                    PQ[(size_t)n * HID + (ch - 64)] = v;
                } else {
                    Pp[(size_t)n * HID + (ch - 128)] = v;
                }
            }
        }
    }
}

// ---- radix pass 1a: per-block LDS histogram of dst>>8 -> transposed block-hist ----
__global__ __launch_bounds__(256) void k_p1hist(const int* __restrict__ ei, int* __restrict__ bhT,
                                                int E, int B1) {
    __shared__ int h[1024];
    int NB1 = gridDim.x;
    for (int i = threadIdx.x; i < B1; i += 256) h[i] = 0;
    __syncthreads();
    int CH = (E + NB1 - 1) / NB1;
    int e0 = blockIdx.x * CH;
    int e1 = min(e0 + CH, E);
    for (int e = e0 + (int)threadIdx.x; e < e1; e += 256)
        atomicAdd(&h[ei[E + e] >> 8], 1);
    __syncthreads();
    for (int i = threadIdx.x; i < B1; i += 256)
        bhT[(size_t)i * NB1 + blockIdx.x] = h[i];
}

// ---- exclusive scan (16/thread, 4096/block) ----
__global__ void k_scan1(const int* __restrict__ cnt, int* __restrict__ rs,
                        int* __restrict__ bsum, int M) {
    __shared__ int lds[256];
    int t = threadIdx.x;
    int base = blockIdx.x * 4096 + t * 16;
    int v[16];
    if (base + 16 <= M) {
#pragma unroll
        for (int u = 0; u < 4; ++u) {
            int4 w = *reinterpret_cast<const int4*>(cnt + base + u * 4);
            v[u * 4 + 0] = w.x; v[u * 4 + 1] = w.y; v[u * 4 + 2] = w.z; v[u * 4 + 3] = w.w;
        }
    } else {
#pragma unroll
        for (int u = 0; u < 16; ++u) v[u] = (base + u < M) ? cnt[base + u] : 0;
    }
    int run = 0;
#pragma unroll
    for (int u = 0; u < 16; ++u) { int tv = v[u]; v[u] = run; run += tv; }
    lds[t] = run;
    __syncthreads();
#pragma unroll
    for (int off = 1; off < 256; off <<= 1) {
        int xw = (t >= off) ? lds[t - off] : 0;
        __syncthreads();
        lds[t] += xw;
        __syncthreads();
    }
    int excl = lds[t] - run;
    if (t == 255) bsum[blockIdx.x] = lds[255];
#pragma unroll
    for (int u = 0; u < 16; ++u)
        if (base + u < M) rs[base + u] = excl + v[u];
}

__global__ void k_scan_add(int* __restrict__ rs, const int* __restrict__ bsum,
                           int NB, int M, int E) {
    __shared__ int lds[256];
    __shared__ int excl[256];
    int t = threadIdx.x;
    int v = (t < NB) ? bsum[t] : 0;
    lds[t] = v;
    __syncthreads();
#pragma unroll
    for (int off = 1; off < 256; off <<= 1) {
        int xw = (t >= off) ? lds[t - off] : 0;
        __syncthreads();
        lds[t] += xw;
        __syncthreads();
    }
    excl[t] = lds[t] - v;
    __syncthreads();
    int i = blockIdx.x * 256 + t;
    if (i < M) rs[i] += excl[i >> 12];
    if (i == 0) rs[M] = E;
}

// ---- radix pass 1b: scatter (src,dst) into bucket-grouped tmp via LDS cursors ----
__global__ __launch_bounds__(256) void k_p1scat(const int* __restrict__ ei, const int* __restrict__ off,
                                                int2* __restrict__ tmp, int E, int B1) {
    __shared__ int cur[1024];
    int NB1 = gridDim.x;
    for (int i = threadIdx.x; i < B1; i += 256)
        cur[i] = off[(size_t)i * NB1 + blockIdx.x];
    __syncthreads();
    int CH = (E + NB1 - 1) / NB1;
    int e0 = blockIdx.x * CH;
    int e1 = min(e0 + CH, E);
    for (int e = e0 + (int)threadIdx.x; e < e1; e += 256) {
        int s = ei[e];
        int d = ei[E + e];
        int pos = atomicAdd(&cur[d >> 8], 1);
        tmp[pos] = make_int2(s, d);
    }
}

// ---- radix pass 2: per-bucket 256-bin LDS counting sort -> flat CSR + row starts ----
__global__ __launch_bounds__(256) void k_p2(const int2* __restrict__ tmp, const int* __restrict__ off,
                                            int* __restrict__ rs, int* __restrict__ csr,
                                            int E, int N, int B1, int NB1) {
    __shared__ int h2[256];
    __shared__ int sc[256];
    __shared__ int cur[256];
    int b = blockIdx.x;
    int t = threadIdx.x;
    int bb0 = off[(size_t)b * NB1];
    int bb1 = off[(size_t)(b + 1) * NB1];   // off[M2] = E covers last bucket

    h2[t] = 0;
    __syncthreads();
    for (int i = bb0 + t; i < bb1; i += 256)
        atomicAdd(&h2[tmp[i].y & 255], 1);
    __syncthreads();

    int v = h2[t];
    sc[t] = v;
    __syncthreads();
#pragma unroll
    for (int o = 1; o < 256; o <<= 1) {
        int xw = (t >= o) ? sc[t - o] : 0;
        __syncthreads();
        sc[t] += xw;
        __syncthreads();
    }
    int excl = sc[t] - v;

    int node = b * 256 + t;
    if (node < N) rs[node] = bb0 + excl;
    if (b == B1 - 1 && t == 0) rs[N] = E;
    cur[t] = bb0 + excl;
    __syncthreads();

    for (int i = bb0 + t; i < bb1; i += 256) {
        int2 ed = tmp[i];
        int pos = atomicAdd(&cur[ed.y & 255], 1);
        csr[pos] = ed.x;
    }
}

// ---- bf16 gather (flat CSR, 2 edges/round per 16-lane group) + elementwise epilogue ----
__global__ __launch_bounds__(256) void k_final(
    const ushort* __restrict__ zb, const float* __restrict__ PQ, const float* __restrict__ Pp,
    const int* __restrict__ rs, const int* __restrict__ csr,
    const float* __restrict__ W2, const float* __restrict__ b2,
    float* __restrict__ out, int N)
{
    int lane = threadIdx.x & 63;
    int g    = lane >> 4;
    int ql   = lane & 15;
    int oct  = ql & 7;
    int half = ql >> 3;
    int wid  = (blockIdx.x * 256 + threadIdx.x) >> 6;
    int nw   = (gridDim.x * 256) >> 6;

    int c0 = oct * 8 + half * 4;
    float4 w2v = *reinterpret_cast<const float4*>(W2 + c0);
    float b2s = b2[0];

    for (int n0 = wid * 4; n0 < N; n0 += nw * 4) {
        int ng   = n0 + g;
        bool okg = ng < N;

        // lanes ql<8 load rs[ng]; ql>=8 load rs[ng+1]
        int rv = okg ? rs[ng + half] : 0;
        int beg = __shfl(rv, g * 16 + 0);
        int end = __shfl(rv, g * 16 + 8);
        int deg = end - beg;
        int md = deg;
        md = max(md, __shfl_xor(md, 16));
        md = max(md, __shfl_xor(md, 32));

        float acc[8];
#pragma unroll
        for (int i = 0; i < 8; ++i) acc[i] = 0.f;

        for (int c = 0; c < md; c += 32) {
            int j0 = c + ql, j1 = c + 16 + ql;
            int ia = (j0 < deg) ? csr[beg + j0] : -1;
            int ib = (j1 < deg) ? csr[beg + j1] : -1;
#pragma unroll
            for (int tb = 0; tb < 4; ++tb) {
                if (tb > 0 && md <= c + 8 * tb) break;
                int srcs[4];
#pragma unroll
                for (int t4 = 0; t4 < 4; ++t4) {
                    int t = tb * 4 + t4;
                    int e = 2 * t + half;
                    srcs[t4] = __shfl(tb < 2 ? ia : ib, g * 16 + (e & 15));
                }
                uint4 rw[4];
#pragma unroll
                for (int t4 = 0; t4 < 4; ++t4) {
                    int s = srcs[t4] < 0 ? 0 : srcs[t4];
                    rw[t4] = *reinterpret_cast<const uint4*>(zb + (size_t)s * HID + oct * 8);
                }
#pragma unroll
                for (int t4 = 0; t4 < 4; ++t4) {
                    if (srcs[t4] >= 0) {
                        uint4 wv = rw[t4];
                        acc[0] += bitsf(wv.x << 16); acc[1] += bitsf(wv.x & 0xffff0000u);
                        acc[2] += bitsf(wv.y << 16); acc[3] += bitsf(wv.y & 0xffff0000u);
                        acc[4] += bitsf(wv.z << 16); acc[5] += bitsf(wv.z & 0xffff0000u);
                        acc[6] += bitsf(wv.w << 16); acc[7] += bitsf(wv.w & 0xffff0000u);
                    }
                }
            }
        }
#pragma unroll
        for (int i = 0; i < 8; ++i) acc[i] += __shfl_xor(acc[i], 8);

        float s0 = half ? acc[4] : acc[0];
        float s1 = half ? acc[5] : acc[1];
        float s2 = half ? acc[6] : acc[2];
        float s3 = half ? acc[7] : acc[3];

        float4 base = make_float4(0.f, 0.f, 0.f, 0.f);
        if (okg) {
            base = *reinterpret_cast<const float4*>(PQ + (size_t)ng * HID + c0);
            if (deg == 0)
                base = *reinterpret_cast<const float4*>(Pp + (size_t)ng * HID + c0);
        }
        float rcpd = (deg > 0) ? (1.f / (float)deg) : 0.f;
        float y0 = base.x + s0 * rcpd;
        float y1 = base.y + s1 * rcpd;
        float y2 = base.z + s2 * rcpd;
        float y3 = base.w + s3 * rcpd;

        float part = fmaxf(y0, 0.f) * w2v.x + fmaxf(y1, 0.f) * w2v.y +
                     fmaxf(y2, 0.f) * w2v.z + fmaxf(y3, 0.f) * w2v.w;
#pragma unroll
        for (int off = 1; off < 16; off <<= 1) part += __shfl_xor(part, off);
        if (ql == 0 && okg) out[ng] = part + b2s;
    }
}

extern "C" void kernel_launch(void* const* d_in, const int* in_sizes, int n_in,
                              void* d_out, int out_size, void* d_ws, size_t ws_size,
                              hipStream_t stream) {
    const float* x   = (const float*)d_in[0];
    const int*   ei  = (const int*)d_in[1];
    const float* W0  = (const float*)d_in[2];
    const float* b0  = (const float*)d_in[3];
    const float* W1  = (const float*)d_in[4];
    const float* b1  = (const float*)d_in[5];
    const float* W2  = (const float*)d_in[6];
    const float* b2  = (const float*)d_in[7];
    const float* M0  = (const float*)d_in[8];
    const float* bM0 = (const float*)d_in[9];

    int N = in_sizes[0] / IN_C;
    int E = in_sizes[1] / 2;
    int B1 = (N + 255) >> 8;            // buckets of 256 nodes (<=1024 for N<=262144)
    int NB1 = 256;                      // pass-1 blocks
    int M2 = B1 * NB1;
    int NB = (M2 + 4095) / 4096;        // scan blocks (<=256)

    ushort* zb     = (ushort*)d_ws;                   // N*64 bf16
    float*  PQ     = (float*)(zb + (size_t)N * HID);  // N*64
    float*  Pp     = PQ + (size_t)N * HID;            // N*64
    ushort* WPhi   = (ushort*)(Pp + (size_t)N * HID); // 12288
    ushort* WPlo   = WPhi + 12288;                    // 12288
    float*  bias192= (float*)(WPlo + 12288);          // 192
    int*    bhT    = (int*)(bias192 + 192);           // M2 (16B aligned)
    int*    off    = bhT + (size_t)M2;                // M2+1
    int*    bsum   = off + (size_t)M2 + 1;            // 256
    int*    rs     = bsum + 256;                      // N+1
    size_t  up     = ((size_t)(rs + N + 1) + 7) & ~(size_t)7;
    int2*   tmp    = (int2*)up;                       // E (8B aligned)
    int*    csr    = (int*)(tmp + (size_t)E);         // E
    float*  out    = (float*)d_out;

    int npre = (N + 63) / 64;

    k_init<<<48, 256, 0, stream>>>(M0, W1, bM0, b1, WPhi, WPlo, bias192);
    k_pre<<<npre, 256, 0, stream>>>(x, W0, b0, WPhi, WPlo, bias192, zb, PQ, Pp, N);
    k_p1hist<<<NB1, 256, 0, stream>>>(ei, bhT, E, B1);
    k_scan1<<<NB, 256, 0, stream>>>(bhT, off, bsum, M2);
    k_scan_add<<<(M2 + 255) / 256, 256, 0, stream>>>(off, bsum, NB, M2, E);
    k_p1scat<<<NB1, 256, 0, stream>>>(ei, off, tmp, E, B1);
    k_p2<<<B1, 256, 0, stream>>>(tmp, off, rs, csr, E, N, B1, NB1);
    k_final<<<2048, 256, 0, stream>>>(zb, PQ, Pp, rs, csr, W2, b2, out, N);
}

// Round 15
// 101.678 us; speedup vs baseline: 1.9663x; 1.1030x over previous
//
#include <hip/hip_runtime.h>

#define HID 64
#define IN_C 16

typedef __attribute__((ext_vector_type(8))) short short8;
typedef __attribute__((ext_vector_type(4))) float f32x4;

__device__ __forceinline__ float bitsf(unsigned u) { return __uint_as_float(u); }
__device__ __forceinline__ unsigned rne16(float f) {
    unsigned u = __float_as_uint(f);
    return (u + 0x7fffu + ((u >> 16) & 1u)) >> 16;
}
__device__ __forceinline__ float lanebcf(float v, int l) {
    return __int_as_float(__builtin_amdgcn_readlane(__float_as_int(v), l));
}
__device__ __forceinline__ float f4c(const float4& a, int c) {
    switch (c & 3) { case 0: return a.x; case 1: return a.y; case 2: return a.z; default: return a.w; }
}

// ---- k_init: pack stacked weights [WZ | W1+WQ | W1] into MFMA frags ----
__global__ void k_init(const float* __restrict__ M0, const float* __restrict__ W1,
                       const float* __restrict__ bM0, const float* __restrict__ b1,
                       ushort* __restrict__ WPhi, ushort* __restrict__ WPlo,
                       float* __restrict__ bias192) {
    int tid = blockIdx.x * 256 + threadIdx.x;
    if (tid >= 64 * 192) return;
    int cc = tid % 192;
    int k  = tid / 192;
    float w;
    if (cc < 64) {
        float a = 0.f;
#pragma unroll
        for (int m = 0; m < HID; ++m) a = fmaf(M0[k * HID + m], W1[m * HID + cc], a);
        w = a;
    } else if (cc < 128) {
        int c = cc - 64;
        float a = W1[k * HID + c];
#pragma unroll
        for (int m = 0; m < HID; ++m) a = fmaf(M0[(HID + k) * HID + m], W1[m * HID + c], a);
        w = a;
    } else {
        w = W1[k * HID + (cc - 128)];
    }
    unsigned wb = __float_as_uint(w);
    ushort hi = (ushort)(wb >> 16);
    float hif = __uint_as_float(wb & 0xffff0000u);
    ushort lo = (ushort)(__float_as_uint(w - hif) >> 16);
    int ct = cc >> 4, s = k >> 5, l = ((k >> 3) & 3) * 16 + (cc & 15), j = k & 7;
    int fi = ((ct * 2 + s) * 64 + l) * 8 + j;
    WPhi[fi] = hi;
    WPlo[fi] = lo;
    if (k == 0) {
        float bv;
        if (cc < 64) bv = 0.f;
        else if (cc < 128) {
            int c = cc - 64;
            float a = b1[c];
#pragma unroll
            for (int m = 0; m < HID; ++m) a = fmaf(bM0[m], W1[m * HID + c], a);
            bv = a;
        } else bv = b1[cc - 128];
        bias192[cc] = bv;
    }
}

// ---- fused: blocks [0,NB1) = LDS radix pass-1 histogram ; rest = MFMA precompute ----
// Transposed MFMA (A=W, B=h): lane holds 4 consecutive CHANNELS of one node -> float4 stores.
__global__ __launch_bounds__(256) void k_pre_hist(
    const float* __restrict__ x, const float* __restrict__ W0, const float* __restrict__ b0,
    const ushort* __restrict__ WPhi, const ushort* __restrict__ WPlo,
    const float* __restrict__ bias192,
    ushort* __restrict__ zb, float* __restrict__ PQ, float* __restrict__ Pp, int N,
    const int* __restrict__ ei, int* __restrict__ bhT, int E, int B1, int NB1)
{
    __shared__ ushort hhi[64 * 64];
    __shared__ ushort hlo[64 * 64];

    if ((int)blockIdx.x < NB1) {
        int* h = reinterpret_cast<int*>(hhi);   // reuse LDS (>=4KB)
        for (int i = threadIdx.x; i < B1; i += 256) h[i] = 0;
        __syncthreads();
        int CH = (E + NB1 - 1) / NB1;
        int e0 = blockIdx.x * CH;
        int e1 = min(e0 + CH, E);
        for (int e = e0 + (int)threadIdx.x; e < e1; e += 256)
            atomicAdd(&h[ei[E + e] >> 8], 1);
        __syncthreads();
        for (int i = threadIdx.x; i < B1; i += 256)
            bhT[(size_t)i * NB1 + blockIdx.x] = h[i];
        return;
    }

    int tid  = threadIdx.x;
    int lane = tid & 63;
    int w    = tid >> 6;
    int n0   = (blockIdx.x - NB1) * 64;

    float w0c[IN_C];
#pragma unroll
    for (int k = 0; k < IN_C; ++k) w0c[k] = W0[k * HID + lane];
    float b0l = b0[lane];

    short8 Whi[3][2], Wlo[3][2];
    float4 bias4[3];
#pragma unroll
    for (int i = 0; i < 3; ++i) {
        int ct = w * 3 + i;
#pragma unroll
        for (int s = 0; s < 2; ++s) {
            int fi = ((ct * 2 + s) * 64 + lane) * 8;
            Whi[i][s] = *reinterpret_cast<const short8*>(WPhi + fi);
            Wlo[i][s] = *reinterpret_cast<const short8*>(WPlo + fi);
        }
        bias4[i] = *reinterpret_cast<const float4*>(bias192 + ct * 16 + (lane >> 4) * 4);
    }

    int nx = n0 + w * 16 + (lane >> 2);
    float4 xq = make_float4(0.f, 0.f, 0.f, 0.f);
    if (nx < N) xq = *reinterpret_cast<const float4*>(x + (size_t)nx * IN_C + (lane & 3) * 4);

    // phase 1: wave-parallel x -> h (16 nodes/wave), split bf16, swizzled LDS
#pragma unroll
    for (int nn = 0; nn < 16; ++nn) {
        float acc = b0l;
#pragma unroll
        for (int k = 0; k < IN_C; ++k)
            acc = fmaf(lanebcf(f4c(xq, k & 3), 4 * nn + (k >> 2)), w0c[k], acc);
        float h = fmaxf(acc, 0.f);
        unsigned hb = __float_as_uint(h);
        ushort hi = (ushort)(hb >> 16);
        float hif = __uint_as_float(hb & 0xffff0000u);
        ushort lo = (ushort)(__float_as_uint(h - hif) >> 16);
        int nl = w * 16 + nn;
        int u  = ((lane >> 3) ^ (nl & 7));
        int off = nl * 64 + u * 8 + (lane & 7);
        hhi[off] = hi;
        hlo[off] = lo;
    }
    __syncthreads();

    // phase 2: transposed MFMA -> vectorized stores
#pragma unroll
    for (int st = 0; st < 4; ++st) {
        int nloc = st * 16 + (lane & 15);
        short8 Ahi[2], Alo[2];
#pragma unroll
        for (int s = 0; s < 2; ++s) {
            int u = (s * 4 + (lane >> 4)) ^ (nloc & 7);
            int off = nloc * 64 + u * 8;
            Ahi[s] = *reinterpret_cast<const short8*>(hhi + off);
            Alo[s] = *reinterpret_cast<const short8*>(hlo + off);
        }
        int n = n0 + st * 16 + (lane & 15);
#pragma unroll
        for (int i = 0; i < 3; ++i) {
            int ct = w * 3 + i;
            f32x4 acc = {bias4[i].x, bias4[i].y, bias4[i].z, bias4[i].w};
#pragma unroll
            for (int s = 0; s < 2; ++s) {
                acc = __builtin_amdgcn_mfma_f32_16x16x32_bf16(Whi[i][s], Ahi[s], acc, 0, 0, 0);
                acc = __builtin_amdgcn_mfma_f32_16x16x32_bf16(Whi[i][s], Alo[s], acc, 0, 0, 0);
                acc = __builtin_amdgcn_mfma_f32_16x16x32_bf16(Wlo[i][s], Ahi[s], acc, 0, 0, 0);
                acc = __builtin_amdgcn_mfma_f32_16x16x32_bf16(Wlo[i][s], Alo[s], acc, 0, 0, 0);
            }
            if (n < N) {
                int chb = ct * 16 + (lane >> 4) * 4;
                if (chb < 64) {
                    uint2 pk;
                    pk.x = rne16(acc[0]) | (rne16(acc[1]) << 16);
                    pk.y = rne16(acc[2]) | (rne16(acc[3]) << 16);
                    *reinterpret_cast<uint2*>(zb + (size_t)n * HID + chb) = pk;
                } else if (chb < 128) {
                    float4 v = make_float4(acc[0], acc[1], acc[2], acc[3]);
                    *reinterpret_cast<float4*>(PQ + (size_t)n * HID + (chb - 64)) = v;
                } else {
                    float4 v = make_float4(acc[0], acc[1], acc[2], acc[3]);
                    *reinterpret_cast<float4*>(Pp + (size_t)n * HID + (chb - 128)) = v;
                }
            }
        }
    }
}

// ---- exclusive scan (16/thread, 4096/block) ----
__global__ void k_scan1(const int* __restrict__ cnt, int* __restrict__ rs,
                        int* __restrict__ bsum, int M) {
    __shared__ int lds[256];
    int t = threadIdx.x;
    int base = blockIdx.x * 4096 + t * 16;
    int v[16];
    if (base + 16 <= M) {
#pragma unroll
        for (int u = 0; u < 4; ++u) {
            int4 w = *reinterpret_cast<const int4*>(cnt + base + u * 4);
            v[u * 4 + 0] = w.x; v[u * 4 + 1] = w.y; v[u * 4 + 2] = w.z; v[u * 4 + 3] = w.w;
        }
    } else {
#pragma unroll
        for (int u = 0; u < 16; ++u) v[u] = (base + u < M) ? cnt[base + u] : 0;
    }
    int run = 0;
#pragma unroll
    for (int u = 0; u < 16; ++u) { int tv = v[u]; v[u] = run; run += tv; }
    lds[t] = run;
    __syncthreads();
#pragma unroll
    for (int off = 1; off < 256; off <<= 1) {
        int xw = (t >= off) ? lds[t - off] : 0;
        __syncthreads();
        lds[t] += xw;
        __syncthreads();
    }
    int excl = lds[t] - run;
    if (t == 255) bsum[blockIdx.x] = lds[255];
#pragma unroll
    for (int u = 0; u < 16; ++u)
        if (base + u < M) rs[base + u] = excl + v[u];
}

__global__ void k_scan_add(int* __restrict__ rs, const int* __restrict__ bsum,
                           int NB, int M, int E) {
    __shared__ int lds[256];
    __shared__ int excl[256];
    int t = threadIdx.x;
    int v = (t < NB) ? bsum[t] : 0;
    lds[t] = v;
    __syncthreads();
#pragma unroll
    for (int off = 1; off < 256; off <<= 1) {
        int xw = (t >= off) ? lds[t - off] : 0;
        __syncthreads();
        lds[t] += xw;
        __syncthreads();
    }
    excl[t] = lds[t] - v;
    __syncthreads();
    int i = blockIdx.x * 256 + t;
    if (i < M) rs[i] += excl[i >> 12];
    if (i == 0) rs[M] = E;
}

// ---- radix pass 1b: scatter packed (src | (dst&255)<<24) via LDS cursors ----
__global__ __launch_bounds__(256) void k_p1scat(const int* __restrict__ ei, const int* __restrict__ off,
                                                unsigned* __restrict__ tmp, int E, int B1) {
    __shared__ int cur[1024];
    int NB1 = gridDim.x;
    for (int i = threadIdx.x; i < B1; i += 256)
        cur[i] = off[(size_t)i * NB1 + blockIdx.x];
    __syncthreads();
    int CH = (E + NB1 - 1) / NB1;
    int e0 = blockIdx.x * CH;
    int e1 = min(e0 + CH, E);
    for (int e = e0 + (int)threadIdx.x; e < e1; e += 256) {
        int s = ei[e];
        int d = ei[E + e];
        int pos = atomicAdd(&cur[d >> 8], 1);
        tmp[pos] = (unsigned)s | ((unsigned)(d & 255) << 24);
    }
}

// ---- radix pass 2: per-bucket 256-bin LDS counting sort -> flat CSR + row starts ----
__global__ __launch_bounds__(256) void k_p2(const unsigned* __restrict__ tmp, const int* __restrict__ off,
                                            int* __restrict__ rs, int* __restrict__ csr,
                                            int E, int N, int B1, int NB1) {
    __shared__ int h2[256];
    __shared__ int sc[256];
    __shared__ int cur[256];
    int b = blockIdx.x;
    int t = threadIdx.x;
    int bb0 = off[(size_t)b * NB1];
    int bb1 = off[(size_t)(b + 1) * NB1];

    h2[t] = 0;
    __syncthreads();
    for (int i = bb0 + t; i < bb1; i += 256)
        atomicAdd(&h2[tmp[i] >> 24], 1);
    __syncthreads();

    int v = h2[t];
    sc[t] = v;
    __syncthreads();
#pragma unroll
    for (int o = 1; o < 256; o <<= 1) {
        int xw = (t >= o) ? sc[t - o] : 0;
        __syncthreads();
        sc[t] += xw;
        __syncthreads();
    }
    int excl = sc[t] - v;

    int node = b * 256 + t;
    if (node < N) rs[node] = bb0 + excl;
    if (b == B1 - 1 && t == 0) rs[N] = E;
    cur[t] = bb0 + excl;
    __syncthreads();

    for (int i = bb0 + t; i < bb1; i += 256) {
        unsigned ed = tmp[i];
        int pos = atomicAdd(&cur[ed >> 24], 1);
        csr[pos] = (int)(ed & 0x00FFFFFFu);
    }
}

// ---- bf16 gather (flat CSR, 2 edges/round per 16-lane group) + elementwise epilogue ----
__global__ __launch_bounds__(256) void k_final(
    const ushort* __restrict__ zb, const float* __restrict__ PQ, const float* __restrict__ Pp,
    const int* __restrict__ rs, const int* __restrict__ csr,
    const float* __restrict__ W2, const float* __restrict__ b2,
    float* __restrict__ out, int N)
{
    int lane = threadIdx.x & 63;
    int g    = lane >> 4;
    int ql   = lane & 15;
    int oct  = ql & 7;
    int half = ql >> 3;
    int wid  = (blockIdx.x * 256 + threadIdx.x) >> 6;
    int nw   = (gridDim.x * 256) >> 6;

    int c0 = oct * 8 + half * 4;
    float4 w2v = *reinterpret_cast<const float4*>(W2 + c0);
    float b2s = b2[0];

    for (int n0 = wid * 4; n0 < N; n0 += nw * 4) {
        int ng   = n0 + g;
        bool okg = ng < N;

        int rv = okg ? rs[ng + half] : 0;
        int beg = __shfl(rv, g * 16 + 0);
        int end = __shfl(rv, g * 16 + 8);
        int deg = end - beg;
        int md = deg;
        md = max(md, __shfl_xor(md, 16));
        md = max(md, __shfl_xor(md, 32));

        float acc[8];
#pragma unroll
        for (int i = 0; i < 8; ++i) acc[i] = 0.f;

        for (int c = 0; c < md; c += 32) {
            int j0 = c + ql, j1 = c + 16 + ql;
            int ia = (j0 < deg) ? csr[beg + j0] : -1;
            int ib = (j1 < deg) ? csr[beg + j1] : -1;
#pragma unroll
            for (int tb = 0; tb < 4; ++tb) {
                if (tb > 0 && md <= c + 8 * tb) break;
                int srcs[4];
#pragma unroll
                for (int t4 = 0; t4 < 4; ++t4) {
                    int t = tb * 4 + t4;
                    int e = 2 * t + half;
                    srcs[t4] = __shfl(tb < 2 ? ia : ib, g * 16 + (e & 15));
                }
                uint4 rw[4];
#pragma unroll
                for (int t4 = 0; t4 < 4; ++t4) {
                    int s = srcs[t4] < 0 ? 0 : srcs[t4];
                    rw[t4] = *reinterpret_cast<const uint4*>(zb + (size_t)s * HID + oct * 8);
                }
#pragma unroll
                for (int t4 = 0; t4 < 4; ++t4) {
                    if (srcs[t4] >= 0) {
                        uint4 wv = rw[t4];
                        acc[0] += bitsf(wv.x << 16); acc[1] += bitsf(wv.x & 0xffff0000u);
                        acc[2] += bitsf(wv.y << 16); acc[3] += bitsf(wv.y & 0xffff0000u);
                        acc[4] += bitsf(wv.z << 16); acc[5] += bitsf(wv.z & 0xffff0000u);
                        acc[6] += bitsf(wv.w << 16); acc[7] += bitsf(wv.w & 0xffff0000u);
                    }
                }
            }
        }
#pragma unroll
        for (int i = 0; i < 8; ++i) acc[i] += __shfl_xor(acc[i], 8);

        float s0 = half ? acc[4] : acc[0];
        float s1 = half ? acc[5] : acc[1];
        float s2 = half ? acc[6] : acc[2];
        float s3 = half ? acc[7] : acc[3];

        float4 base = make_float4(0.f, 0.f, 0.f, 0.f);
        if (okg) {
            base = *reinterpret_cast<const float4*>(PQ + (size_t)ng * HID + c0);
            if (deg == 0)
                base = *reinterpret_cast<const float4*>(Pp + (size_t)ng * HID + c0);
        }
        float rcpd = (deg > 0) ? (1.f / (float)deg) : 0.f;
        float y0 = base.x + s0 * rcpd;
        float y1 = base.y + s1 * rcpd;
        float y2 = base.z + s2 * rcpd;
        float y3 = base.w + s3 * rcpd;

        float part = fmaxf(y0, 0.f) * w2v.x + fmaxf(y1, 0.f) * w2v.y +
                     fmaxf(y2, 0.f) * w2v.z + fmaxf(y3, 0.f) * w2v.w;
#pragma unroll
        for (int off = 1; off < 16; off <<= 1) part += __shfl_xor(part, off);
        if (ql == 0 && okg) out[ng] = part + b2s;
    }
}

extern "C" void kernel_launch(void* const* d_in, const int* in_sizes, int n_in,
                              void* d_out, int out_size, void* d_ws, size_t ws_size,
                              hipStream_t stream) {
    const float* x   = (const float*)d_in[0];
    const int*   ei  = (const int*)d_in[1];
    const float* W0  = (const float*)d_in[2];
    const float* b0  = (const float*)d_in[3];
    const float* W1  = (const float*)d_in[4];
    const float* b1  = (const float*)d_in[5];
    const float* W2  = (const float*)d_in[6];
    const float* b2  = (const float*)d_in[7];
    const float* M0  = (const float*)d_in[8];
    const float* bM0 = (const float*)d_in[9];

    int N = in_sizes[0] / IN_C;
    int E = in_sizes[1] / 2;
    int B1 = (N + 255) >> 8;            // buckets of 256 nodes
    int NB1 = 256;                      // pass-1 blocks
    int M2 = B1 * NB1;
    int NB = (M2 + 4095) / 4096;        // scan blocks (<=256)

    ushort*   zb     = (ushort*)d_ws;                   // N*64 bf16
    float*    PQ     = (float*)(zb + (size_t)N * HID);  // N*64
    float*    Pp     = PQ + (size_t)N * HID;            // N*64
    ushort*   WPhi   = (ushort*)(Pp + (size_t)N * HID); // 12288
    ushort*   WPlo   = WPhi + 12288;                    // 12288
    float*    bias192= (float*)(WPlo + 12288);          // 192
    int*      bhT    = (int*)(bias192 + 192);           // M2
    int*      off    = bhT + (size_t)M2;                // M2+1
    int*      bsum   = off + (size_t)M2 + 1;            // 256
    int*      rs     = bsum + 256;                      // N+1
    unsigned* tmp    = (unsigned*)(rs + N + 1);         // E (packed)
    int*      csr    = (int*)(tmp + (size_t)E);         // E
    float*    out    = (float*)d_out;

    int npre = (N + 63) / 64;

    k_init<<<48, 256, 0, stream>>>(M0, W1, bM0, b1, WPhi, WPlo, bias192);
    k_pre_hist<<<NB1 + npre, 256, 0, stream>>>(x, W0, b0, WPhi, WPlo, bias192,
                                               zb, PQ, Pp, N, ei, bhT, E, B1, NB1);
    k_scan1<<<NB, 256, 0, stream>>>(bhT, off, bsum, M2);
    k_scan_add<<<(M2 + 255) / 256, 256, 0, stream>>>(off, bsum, NB, M2, E);
    k_p1scat<<<NB1, 256, 0, stream>>>(ei, off, tmp, E, B1);
    k_p2<<<B1, 256, 0, stream>>>(tmp, off, rs, csr, E, N, B1, NB1);
    k_final<<<2048, 256, 0, stream>>>(zb, PQ, Pp, rs, csr, W2, b2, out, N);
}